// Round 1
// 261.534 us; speedup vs baseline: 1.2304x; 1.2304x over previous
//
#include <hip/hip_runtime.h>

// fCGModule: Clebsch-Gordan tensor product, MAXL=5, TAUS=16, BATCH=256.
// Output = tuple out0..out5 concatenated flat; out_l shape (256, nfrag_l*256, 2l+1, 2) fp32.
// Write floor ~40us @6.3TB/s (239.6 MB out).
// R3: CG coefficients moved to COMPILE TIME (constexpr factorial/sqrt + template
// recursion -> literal operands, structural zeros pruned). Eliminates the 256x-redundant
// FP64 prologue, the per-combo LDS c-loads, and the 6x wr/wi recompute (l now inner,
// full per-pair accumulator in registers). Epilogue keeps the R2 LDS-staged float4
// coalesced copy but ping-pongs two staging buffers (1 barrier per l instead of 2);
// l=0 (NM=1) stores direct float2 (already lane-contiguous).

// ---------------- compile-time CG math ----------------
constexpr double CFACT[17] = {
    1.0, 1.0, 2.0, 6.0, 24.0, 120.0, 720.0, 5040.0, 40320.0, 362880.0,
    3628800.0, 39916800.0, 479001600.0, 6227020800.0, 87178291200.0,
    1307674368000.0, 20922789888000.0};

constexpr double csqrt_ce(double x) {
    double g = x > 1.0 ? x : 1.0;   // never 0 -> no div-by-zero in constexpr
    for (int i = 0; i < 60; ++i) g = 0.5 * (g + x / g);
    return g;
}

// exact Condon-Shortley CG coefficient (mirrors reference _cg), constexpr
constexpr double cg_ce(int l1, int l2, int l, int m1, int m2) {
    int m = m1 + m2;
    if (m > l || -m > l || l < l1 - l2 || l > l1 + l2) return 0.0;
    double pref = (double)(2 * l + 1) * CFACT[l + l1 - l2] * CFACT[l - l1 + l2] *
                  CFACT[l1 + l2 - l] / CFACT[l1 + l2 + l + 1];
    pref *= CFACT[l + m] * CFACT[l - m] * CFACT[l1 - m1] * CFACT[l1 + m1] *
            CFACT[l2 - m2] * CFACT[l2 + m2];
    int kmin = 0;
    if (-(l - l2 + m1) > kmin) kmin = -(l - l2 + m1);
    if (-(l - l1 - m2) > kmin) kmin = -(l - l1 - m2);
    int kmax = l1 + l2 - l;
    if (l1 - m1 < kmax) kmax = l1 - m1;
    if (l2 + m2 < kmax) kmax = l2 + m2;
    double s = 0.0;
    for (int k = kmin; k <= kmax; ++k) {
        double d = CFACT[k] * CFACT[l1 + l2 - l - k] * CFACT[l1 - m1 - k] *
                   CFACT[l2 + m2 - k] * CFACT[l - l2 + m1 + k] * CFACT[l - l1 - m2 + k];
        s += ((k & 1) ? -1.0 : 1.0) / d;
    }
    return csqrt_ce(pref) * s;
}

// ---- compile-time layout tables (derived from _TRIPLES ordering; validated R1) ----
constexpr int OUT_BASE[6]  = {0, 786432, 4718592, 13238272, 26083328, 42598400};
constexpr int STRIDE_B[6]  = {3072, 15360, 33280, 50176, 64512, 67584}; // NCH_l*(2l+1)*2

// 21 (l1,l2) pairs ordered by descending work (heavy blocks dispatch first)
constexpr int PL1[21] = {5,5,4,4,5,3,4,3,5,2,4,5,3,2,1,5,4,3,2,1,0};
constexpr int PL2[21] = {5,4,4,3,3,3,2,2,2,2,1,1,1,1,1,0,0,0,0,0,0};
constexpr int PFRAG[21][6] = {
    { 5,  9, 12, 13, 13, 11},  // (5,5)
    {-1,  8, 11, 12, 12, 10},  // (5,4)
    { 4,  7,  9,  9,  8,  5},  // (4,4)
    {-1,  6,  8,  8,  7,  4},  // (4,3)
    {-1, -1, 10, 11, 11,  9},  // (5,3)
    { 3,  5,  6,  5,  3,  1},  // (3,3)
    {-1, -1,  7,  7,  6,  3},  // (4,2)
    {-1,  4,  5,  4,  2,  0},  // (3,2)
    {-1, -1, -1, 10, 10,  8},  // (5,2)
    { 2,  3,  3,  1,  0, -1},  // (2,2)
    {-1, -1, -1,  6,  5,  2},  // (4,1)
    {-1, -1, -1, -1,  9,  7},  // (5,1)
    {-1, -1,  4,  3,  1, -1},  // (3,1)
    {-1,  2,  2,  0, -1, -1},  // (2,1)
    { 1,  1,  0, -1, -1, -1},  // (1,1)
    {-1, -1, -1, -1, -1,  6},  // (5,0)
    {-1, -1, -1, -1,  4, -1},  // (4,0)
    {-1, -1, -1,  2, -1, -1},  // (3,0)
    {-1, -1,  1, -1, -1, -1},  // (2,0)
    {-1,  0, -1, -1, -1, -1},  // (1,0)
    { 0, -1, -1, -1, -1, -1},  // (0,0)
};

// ---------------- template-recursive fully-unrolled accumulation ----------------
// Every CG coefficient is a constexpr float literal; zeros are pruned at the
// front end (if constexpr), so no runtime branches and no table storage at all.

template <int L1, int L2, int P, int Q, int LV>
__device__ __forceinline__ void accum_l(float wr, float wi, float* ar, float* ai) {
    constexpr int LMIN = L1 - L2;
    constexpr int LMAX = (L1 + L2 < 5) ? (L1 + L2) : 5;
    constexpr int M  = (P - L1) + (Q - L2);
    constexpr int AM = M < 0 ? -M : M;
    if constexpr (AM <= LV) {
        constexpr float c = (float)cg_ce(L1, L2, LV, P - L1, Q - L2);
        if constexpr (c != 0.0f) {
            constexpr int idx = LV * LV - LMIN * LMIN + M + LV; // acc block offset + (m+l)
            ar[idx] += c * wr;
            ai[idx] += c * wi;
        }
    }
    if constexpr (LV < LMAX) accum_l<L1, L2, P, Q, LV + 1>(wr, wi, ar, ai);
}

template <int L1, int L2, int P, int Q>
__device__ __forceinline__ void do_q(const float2* z1, const float2* z2,
                                     float* ar, float* ai) {
    // complex product computed ONCE per (p,q); dead-code-eliminated if every l pruned
    float wr = z1[P].x * z2[Q].x - z1[P].y * z2[Q].y;
    float wi = z1[P].x * z2[Q].y + z1[P].y * z2[Q].x;
    accum_l<L1, L2, P, Q, L1 - L2>(wr, wi, ar, ai);
    if constexpr (Q + 1 < 2 * L2 + 1) do_q<L1, L2, P, Q + 1>(z1, z2, ar, ai);
}

template <int L1, int L2, int P>
__device__ __forceinline__ void do_p(const float2* z1, const float2* z2,
                                     float* ar, float* ai) {
    do_q<L1, L2, P, 0>(z1, z2, ar, ai);
    if constexpr (P + 1 < 2 * L1 + 1) do_p<L1, L2, P + 1>(z1, z2, ar, ai);
}

template <int PAIR>
__device__ __forceinline__ void pair_body(const float* const acts[6],
                                          float* __restrict__ out,
                                          int b, int tid, float* stage) {
    constexpr int L1   = PL1[PAIR];
    constexpr int L2   = PL2[PAIR];
    constexpr int LMIN = L1 - L2;
    constexpr int LMAX = (L1 + L2 < 5) ? (L1 + L2) : 5;
    constexpr int N1   = 2 * L1 + 1;
    constexpr int N2   = 2 * L2 + 1;
    constexpr int NTOT = (LMAX + 1) * (LMAX + 1) - LMIN * LMIN; // sum of (2l+1)

    const int i = tid >> 4;   // channel of act[L1]
    const int j = tid & 15;   // channel of act[L2]

    const float2* __restrict__ z1p =
        (const float2*)(acts[L1] + (size_t)(b * 16 + i) * N1 * 2);
    const float2* __restrict__ z2p =
        (const float2*)(acts[L2] + (size_t)(b * 16 + j) * N2 * 2);
    float2 z1[N1], z2[N2];
#pragma unroll
    for (int p = 0; p < N1; ++p) z1[p] = z1p[p];
#pragma unroll
    for (int q = 0; q < N2; ++q) z2[q] = z2p[q];

    // full accumulator set for ALL output l simultaneously (<=72 VGPRs for (5,5))
    float ar[NTOT], ai[NTOT];
#pragma unroll
    for (int k = 0; k < NTOT; ++k) { ar[k] = 0.f; ai[k] = 0.f; }

    do_p<L1, L2, 0>(z1, z2, ar, ai);

    // epilogue: per l, stage block-contiguous in LDS (ping-pong buffers -> one
    // barrier per l), copy out float4-coalesced. l=0 is already coalesced direct.
#pragma unroll
    for (int l = LMIN; l <= LMAX; ++l) {
        const int NM   = 2 * l + 1;
        const int off  = l * l - LMIN * LMIN;
        const int frag = PFRAG[PAIR][l];
        if (NM == 1) {
            // NM==1 only happens at the first l of a pair -> never between staged ls
            float2* __restrict__ d2 = (float2*)(out + OUT_BASE[l] +
                (size_t)b * STRIDE_B[l] + (size_t)frag * 512);
            d2[tid] = make_float2(ar[off], ai[off]);
        } else {
            float* sb = stage + (size_t)((l - LMIN) & 1) * 5632;
            float2* st = (float2*)sb + tid * NM;
#pragma unroll
            for (int k = 0; k < NM; ++k) st[k] = make_float2(ar[off + k], ai[off + k]);
            __syncthreads();
            // coalesced copy: 256*NM float2 = 128*NM float4, lane-contiguous
            const float4* __restrict__ s4 = (const float4*)sb;
            float4* __restrict__ d4 = (float4*)(out + OUT_BASE[l] +
                (size_t)b * STRIDE_B[l] + (size_t)frag * 512 * NM);
            const int cnt = 128 * NM;
            for (int k = tid; k < cnt; k += 256) d4[k] = s4[k];
            // no trailing barrier: next l stages into the OTHER buffer; this
            // buffer is reused only after the next staged-l barrier.
        }
    }
}

__global__ __launch_bounds__(256, 3) void fCG_kernel(
    const float* __restrict__ a0, const float* __restrict__ a1,
    const float* __restrict__ a2, const float* __restrict__ a3,
    const float* __restrict__ a4, const float* __restrict__ a5,
    float* __restrict__ out) {
    __shared__ __align__(16) float stage[2 * 5632];   // ping-pong, 45 KB
    const float* acts[6] = {a0, a1, a2, a3, a4, a5};
    int pair = blockIdx.x >> 8;   // 256 blocks per pair (one per batch element)
    int b    = blockIdx.x & 255;
    int tid  = threadIdx.x;
    switch (pair) {
        case 0:  pair_body<0>(acts, out, b, tid, stage); break;
        case 1:  pair_body<1>(acts, out, b, tid, stage); break;
        case 2:  pair_body<2>(acts, out, b, tid, stage); break;
        case 3:  pair_body<3>(acts, out, b, tid, stage); break;
        case 4:  pair_body<4>(acts, out, b, tid, stage); break;
        case 5:  pair_body<5>(acts, out, b, tid, stage); break;
        case 6:  pair_body<6>(acts, out, b, tid, stage); break;
        case 7:  pair_body<7>(acts, out, b, tid, stage); break;
        case 8:  pair_body<8>(acts, out, b, tid, stage); break;
        case 9:  pair_body<9>(acts, out, b, tid, stage); break;
        case 10: pair_body<10>(acts, out, b, tid, stage); break;
        case 11: pair_body<11>(acts, out, b, tid, stage); break;
        case 12: pair_body<12>(acts, out, b, tid, stage); break;
        case 13: pair_body<13>(acts, out, b, tid, stage); break;
        case 14: pair_body<14>(acts, out, b, tid, stage); break;
        case 15: pair_body<15>(acts, out, b, tid, stage); break;
        case 16: pair_body<16>(acts, out, b, tid, stage); break;
        case 17: pair_body<17>(acts, out, b, tid, stage); break;
        case 18: pair_body<18>(acts, out, b, tid, stage); break;
        case 19: pair_body<19>(acts, out, b, tid, stage); break;
        case 20: pair_body<20>(acts, out, b, tid, stage); break;
        default: break;
    }
}

extern "C" void kernel_launch(void* const* d_in, const int* in_sizes, int n_in,
                              void* d_out, int out_size, void* d_ws, size_t ws_size,
                              hipStream_t stream) {
    const float* a0 = (const float*)d_in[0];
    const float* a1 = (const float*)d_in[1];
    const float* a2 = (const float*)d_in[2];
    const float* a3 = (const float*)d_in[3];
    const float* a4 = (const float*)d_in[4];
    const float* a5 = (const float*)d_in[5];
    float* out = (float*)d_out;
    // 21 pairs x 256 blocks (one per batch) x 256 threads (i*16+j)
    fCG_kernel<<<dim3(21 * 256), dim3(256), 0, stream>>>(a0, a1, a2, a3, a4, a5, out);
}